// Round 3
// baseline (503.270 us; speedup 1.0000x reference)
//
#include <hip/hip_runtime.h>
#include <hip/hip_bf16.h>
#include <stdint.h>

// R7 (466.7us): unfused, BM=128xBN=256, 2 blocks/CU.
// R8 (498.1us): fused LN, BM=64xBN=512 -> B restaged 805MB, gemms +30us each.
// R9 (CRASH): 160KB static LDS (= full pool) -> suspect module/launch abort.
//   (verified example ceiling is 128KB static; AITER's 160KB is hand-asm .co)
// R10: fused, BM=128xBN=512, 8 waves, BK=32 DOUBLE-buffered (80KB LDS, safe),
//   m248v2-verified 2-phase pipeline: STAGE(next tile) -> ds_read+MFMA(cur)
//   -> __syncthreads() (its vmcnt(0) drain is ~free: loads had the whole
//   ~1240cy MFMA phase to land). No inline asm anywhere.
//   Swizzle for 64B rows: slot = kslot ^ (r&3) ^ ((r>>2)&3) (2-way max = free),
//   applied as pre-swizzled global SOURCE + swizzled READ (linear LDS dest).

typedef _Float16 f16;
typedef _Float16 f16x8 __attribute__((ext_vector_type(8)));
typedef float f32x4 __attribute__((ext_vector_type(4)));

#define B_    32
#define T_    1024
#define TP_   1026
#define C_    512
#define LMAX_ 4096
#define KDIM  1536
#define NK    48          // KDIM / 32

// workspace byte offsets (all 256-aligned)
#define XPAD_OFF   0u
#define H1PAD_OFF  33619968u     // 32*1026*512*2
#define W1T_OFF    67239936u
#define W2T_OFF    68812800u
#define TOT_OFF    137494528u
#define IDX_OFF    137495040u

#define AS1C(p) ((const __attribute__((address_space(1))) void*)(p))
#define AS3(p)  ((__attribute__((address_space(3))) void*)(p))

// ---------------------------------------------------------------------------
__global__ __launch_bounds__(256) void prep_pad(const float* __restrict__ batch,
                                                f16* __restrict__ xpad,
                                                f16* __restrict__ h1pad) {
    int row = blockIdx.x * 4 + (threadIdx.x >> 6);   // 0 .. B_*TP_-1
    int lane = threadIdx.x & 63;
    int b = row / TP_, tt = row % TP_;
    size_t dsto = (size_t)row * C_ + lane * 8;
    if (tt == 0 || tt == TP_ - 1) {
        f16x8 z = {};
        *(f16x8*)(xpad + dsto) = z;
        *(f16x8*)(h1pad + dsto) = z;
    } else {
        const float* src = batch + ((size_t)(b * T_ + tt - 1)) * C_ + lane * 8;
        float4 v0 = ((const float4*)src)[0];
        float4 v1 = ((const float4*)src)[1];
        f16x8 h;
        h[0] = (f16)v0.x; h[1] = (f16)v0.y; h[2] = (f16)v0.z; h[3] = (f16)v0.w;
        h[4] = (f16)v1.x; h[5] = (f16)v1.y; h[6] = (f16)v1.z; h[7] = (f16)v1.w;
        *(f16x8*)(xpad + dsto) = h;
    }
}

// ---------------------------------------------------------------------------
__global__ __launch_bounds__(256) void prep_w(const float* __restrict__ w1,
                                              const float* __restrict__ w2,
                                              f16* __restrict__ w1t,
                                              f16* __restrict__ w2t) {
    int o = blockIdx.x;
    const float* w = blockIdx.y ? w2 : w1;
    f16* wt = blockIdx.y ? w2t : w1t;
    for (int j = threadIdx.x; j < KDIM; j += 256) {
        int tap = j >> 9, i = j & 511;
        wt[(size_t)o * KDIM + j] = (f16)w[(size_t)o * KDIM + i * 3 + tap];
    }
}

// ---------------------------------------------------------------------------
__global__ __launch_bounds__(1024) void scan_kernel(const int* __restrict__ dur,
                                                    const int* __restrict__ tlen,
                                                    int* __restrict__ idxarr,
                                                    int* __restrict__ total,
                                                    float* __restrict__ mel_out) {
    int b = blockIdx.x, t = threadIdx.x;
    __shared__ int sd[1024];
    __shared__ int sv[1024];
    int L = tlen[b];
    int valid = (t < L) ? 1 : 0;
    int d = valid ? dur[b * T_ + t] : 0;
    sd[t] = d; sv[t] = valid;
    __syncthreads();
    for (int off = 1; off < 1024; off <<= 1) {
        int x = 0, y = 0;
        if (t >= off) { x = sd[t - off]; y = sv[t - off]; }
        __syncthreads();
        sd[t] += x; sv[t] += y;
        __syncthreads();
    }
    int totd = sd[1023];
    int cur  = (totd == 0) ? sv[t] : sd[t];
    int prev = (t == 0) ? 0 : ((totd == 0) ? sv[t - 1] : sd[t - 1]);
    for (int f = prev; f < cur; f++) idxarr[b * LMAX_ + f] = t;
    if (t == 1023) {
        int tt = (totd == 0) ? sv[1023] : totd;
        total[b] = tt;
        mel_out[b] = (float)tt;
    }
}

// ---------------------------------------------------------------------------
// implicit-GEMM conv fused with LayerNorm epilogue.
// BM=128 x BN=512, 8 waves (2M x 4N), wave tile 64x128 (4x8 frags 16x16x32).
// BK=32, double-buffered (80KB LDS), 2-phase pipeline (stage-next / compute /
// __syncthreads).  Per iter per wave: 5 global_load_lds (1 A + 4 B),
// 12 ds_read_b128, 32 MFMA.
// LDS row = 32 f16 = 4 granules of 16B; LDS[r][s] holds global granule
// s ^ (r&3) ^ ((r>>2)&3)  (involution; staging pre-swizzles the SOURCE,
// reads apply the same XOR; dest stays linear for global_load_lds).
template<int EPI>
__global__ __launch_bounds__(512, 2) void gemm_fused(const f16* __restrict__ A,
                                                     const f16* __restrict__ Bw,
                                                     const float* __restrict__ bias,
                                                     const float* __restrict__ g,
                                                     const float* __restrict__ be,
                                                     const float* __restrict__ lw,
                                                     const float* __restrict__ lb,
                                                     const int* __restrict__ tlen,
                                                     f16* __restrict__ hpad,
                                                     float* __restrict__ pred) {
    __shared__ f16 lds_[40960];          // 80 KB: A0|A1|B0|B1
    f16* const A0 = lds_;                // 128*32 = 4096 f16 (8 KB)
    f16* const A1 = lds_ + 4096;
    f16* const B0 = lds_ + 8192;         // 512*32 = 16384 f16 (32 KB)
    f16* const B1 = lds_ + 24576;
    float* red = (float*)lds_;           // epilogue scratch, aliases A0/A1

    const int tid = threadIdx.x;
    const int lane = tid & 63;
    const int w = tid >> 6;              // 0..7
    const int wm = (w & 1) * 64;         // wave M offset
    const int wn = (w >> 1) * 128;       // wave N offset
    const int m0 = blockIdx.x * 128;
    const int arow0 = (m0 >> 10) * TP_ + (m0 & 1023);

    f32x4 acc[4][8];
#pragma unroll
    for (int i = 0; i < 4; i++)
#pragma unroll
        for (int j = 0; j < 8; j++) acc[i][j] = (f32x4){0.f, 0.f, 0.f, 0.f};

    // swizzle permutation (same value serves staging-source and read-slot)
    const int perm = (lane & 3) ^ ((lane >> 2) & 3) ^ ((lane >> 4) & 3);
    // staging source bases: lane covers row (base + lane>>2), granule perm
    const f16* aB = A + (size_t)(arow0 + w * 16 + (lane >> 2)) * C_ + perm * 8;
    const f16* bB = Bw + (size_t)(w * 16 + (lane >> 2)) * KDIM + perm * 8;

#define STAGE(Ad, Bd, kofs) do {                                              \
        __builtin_amdgcn_global_load_lds(AS1C(aB + (kofs)),                   \
                                         AS3((Ad) + w * 512), 16, 0, 0);      \
        _Pragma("unroll")                                                     \
        for (int j_ = 0; j_ < 4; j_++) {                                      \
            __builtin_amdgcn_global_load_lds(                                 \
                AS1C(bB + (size_t)(128 * j_) * KDIM + (kofs)),                \
                AS3((Bd) + (w + 8 * j_) * 512), 16, 0, 0);                    \
        }                                                                     \
    } while (0)

    STAGE(A0, B0, 0);                    // prologue: tile 0
    __syncthreads();

    f16 *Ac = A0, *An = A1, *Bc = B0, *Bn = B1;
    for (int t = 0; t < NK; ++t) {
        if (t + 1 < NK) STAGE(An, Bn, (t + 1) * 32);   // next tile in flight
        const int base = perm * 8;
        f16x8 af[4], bf[8];
#pragma unroll
        for (int mi = 0; mi < 4; mi++)
            af[mi] = *(const f16x8*)&Ac[(wm + mi * 16 + (lane & 15)) * 32 + base];
#pragma unroll
        for (int ni = 0; ni < 8; ni++)
            bf[ni] = *(const f16x8*)&Bc[(wn + ni * 16 + (lane & 15)) * 32 + base];
#pragma unroll
        for (int mi = 0; mi < 4; mi++)
#pragma unroll
            for (int ni = 0; ni < 8; ni++)
                acc[mi][ni] = __builtin_amdgcn_mfma_f32_16x16x32_f16(
                    af[mi], bf[ni], acc[mi][ni], 0, 0, 0);
        __syncthreads();                 // drains stage writes + frag reads
        f16* tp;
        tp = Ac; Ac = An; An = tp;
        tp = Bc; Bc = Bn; Bn = tp;
    }
#undef STAGE

    // ---------------- fused epilogue ----------------
    const int col = lane & 15;
    const int row4 = (lane >> 4) * 4;
    const int nw = w >> 1;               // N-wave index 0..3

    float bn[8];
#pragma unroll
    for (int ni = 0; ni < 8; ni++) bn[ni] = bias[wn + ni * 16 + col];
    float s_[4][4], q_[4][4];
#pragma unroll
    for (int mi = 0; mi < 4; mi++)
#pragma unroll
        for (int r = 0; r < 4; r++) { s_[mi][r] = 0.f; q_[mi][r] = 0.f; }
#pragma unroll
    for (int mi = 0; mi < 4; mi++)
#pragma unroll
        for (int ni = 0; ni < 8; ni++)
#pragma unroll
            for (int r = 0; r < 4; r++) {
                float v = acc[mi][ni][r] + bn[ni];
                v = v > 0.f ? v : 0.f;
                acc[mi][ni][r] = v;
                s_[mi][r] += v;
                q_[mi][r] += v * v;
            }
    // reduce across the 16 col-lanes (same rows live at same lane>>4)
#pragma unroll
    for (int m = 8; m; m >>= 1)
#pragma unroll
        for (int mi = 0; mi < 4; mi++)
#pragma unroll
            for (int r = 0; r < 4; r++) {
                s_[mi][r] += __shfl_xor(s_[mi][r], m, 64);
                q_[mi][r] += __shfl_xor(q_[mi][r], m, 64);
            }
    // cross-wave reduce via LDS (4 N-wave groups hold disjoint col ranges)
    if (col == 0) {
#pragma unroll
        for (int mi = 0; mi < 4; mi++)
#pragma unroll
            for (int r = 0; r < 4; r++) {
                int row = wm + mi * 16 + row4 + r;     // 0..127
                red[(nw * 128 + row) * 2]     = s_[mi][r];
                red[(nw * 128 + row) * 2 + 1] = q_[mi][r];
            }
    }
    __syncthreads();
    float mu_[4][4], rs_[4][4];
#pragma unroll
    for (int mi = 0; mi < 4; mi++)
#pragma unroll
        for (int r = 0; r < 4; r++) {
            int row = wm + mi * 16 + row4 + r;
            float S = red[row * 2]             + red[(128 + row) * 2]
                    + red[(256 + row) * 2]     + red[(384 + row) * 2];
            float Q = red[row * 2 + 1]         + red[(128 + row) * 2 + 1]
                    + red[(256 + row) * 2 + 1] + red[(384 + row) * 2 + 1];
            float mu = S * (1.f / 512.f);
            float x = Q * (1.f / 512.f) - mu * mu + 1e-5f;
            float rs = rsqrtf(x);
            rs = rs * (1.5f - 0.5f * x * rs * rs);   // Newton refine
            mu_[mi][r] = mu; rs_[mi][r] = rs;
        }

    if (EPI == 0) {
        // LN -> f16 hpad at (b, t+1)
        const int bb = m0 >> 10, t0 = m0 & 1023;
        f16* hbase = hpad + ((size_t)(bb * TP_ + t0 + 1)) * C_;
#pragma unroll
        for (int ni = 0; ni < 8; ni++) {
            int n = wn + ni * 16 + col;
            float gv = g[n], ev = be[n];
#pragma unroll
            for (int mi = 0; mi < 4; mi++)
#pragma unroll
                for (int r = 0; r < 4; r++) {
                    int lm = wm + mi * 16 + row4 + r;
                    float v = (acc[mi][ni][r] - mu_[mi][r]) * rs_[mi][r] * gv + ev;
                    hbase[(size_t)lm * C_ + n] = (f16)v;
                }
        }
    } else {
        // LN + Linear head -> pred[m], masked by token length
        float p_[4][4];
#pragma unroll
        for (int mi = 0; mi < 4; mi++)
#pragma unroll
            for (int r = 0; r < 4; r++) p_[mi][r] = 0.f;
#pragma unroll
        for (int ni = 0; ni < 8; ni++) {
            int n = wn + ni * 16 + col;
            float gv = g[n], ev = be[n], wv = lw[n];
#pragma unroll
            for (int mi = 0; mi < 4; mi++)
#pragma unroll
                for (int r = 0; r < 4; r++)
                    p_[mi][r] += ((acc[mi][ni][r] - mu_[mi][r]) * rs_[mi][r] * gv + ev) * wv;
        }
#pragma unroll
        for (int m = 8; m; m >>= 1)
#pragma unroll
            for (int mi = 0; mi < 4; mi++)
#pragma unroll
                for (int r = 0; r < 4; r++)
                    p_[mi][r] += __shfl_xor(p_[mi][r], m, 64);
        __syncthreads();   // all red[] stat reads complete before reuse
        if (col == 0) {
#pragma unroll
            for (int mi = 0; mi < 4; mi++)
#pragma unroll
                for (int r = 0; r < 4; r++)
                    red[nw * 128 + wm + mi * 16 + row4 + r] = p_[mi][r];
        }
        __syncthreads();
        if (tid < 128) {
            int m = m0 + tid;
            float p = red[tid] + red[128 + tid] + red[256 + tid] + red[384 + tid];
            int bb = m >> 10, t = m & 1023;
            pred[m] = (t < tlen[bb]) ? (p + lb[0]) : 0.f;
        }
    }
}

// ---------------------------------------------------------------------------
__global__ __launch_bounds__(256) void gather_kernel(const float* __restrict__ batch,
                                                     const int* __restrict__ idxarr,
                                                     const int* __restrict__ total,
                                                     float* __restrict__ out) {
    int gw = blockIdx.x * 4 + (threadIdx.x >> 6);  // 0 .. B_*LMAX_-1
    int lane = threadIdx.x & 63;
    int b = gw >> 12;
    int l = gw & (LMAX_ - 1);
    int tot = total[b];
    float4* dst = (float4*)(out + ((size_t)b * LMAX_ + l) * C_);
    if (l < tot) {
        int idx = idxarr[gw];
        const float4* src = (const float4*)(batch + ((size_t)b * T_ + idx) * C_);
        dst[lane] = src[lane];
        dst[lane + 64] = src[lane + 64];
    } else {
        float4 z = {0.f, 0.f, 0.f, 0.f};
        dst[lane] = z;
        dst[lane + 64] = z;
    }
}

// ---------------------------------------------------------------------------
extern "C" void kernel_launch(void* const* d_in, const int* in_sizes, int n_in,
                              void* d_out, int out_size, void* d_ws, size_t ws_size,
                              hipStream_t stream) {
    const float* batch = (const float*)d_in[0];
    const int* tlen    = (const int*)d_in[1];
    const int* durs    = (const int*)d_in[3];
    const float* w1  = (const float*)d_in[4];
    const float* b1  = (const float*)d_in[5];
    const float* g1  = (const float*)d_in[6];
    const float* be1 = (const float*)d_in[7];
    const float* w2  = (const float*)d_in[8];
    const float* b2  = (const float*)d_in[9];
    const float* g2  = (const float*)d_in[10];
    const float* be2 = (const float*)d_in[11];
    const float* lw  = (const float*)d_in[12];
    const float* lb  = (const float*)d_in[13];

    float* out      = (float*)d_out;
    float* mel_out  = out + (size_t)B_ * LMAX_ * C_;
    float* pred_out = mel_out + B_;

    char* ws    = (char*)d_ws;
    f16* xpad   = (f16*)(ws + XPAD_OFF);
    f16* h1pad  = (f16*)(ws + H1PAD_OFF);
    f16* w1t    = (f16*)(ws + W1T_OFF);
    f16* w2t    = (f16*)(ws + W2T_OFF);
    int* tot    = (int*)(ws + TOT_OFF);
    int* idxarr = (int*)(ws + IDX_OFF);

    prep_pad<<<B_ * TP_ / 4, 256, 0, stream>>>(batch, xpad, h1pad);
    prep_w<<<dim3(512, 2), 256, 0, stream>>>(w1, w2, w1t, w2t);
    scan_kernel<<<B_, 1024, 0, stream>>>(durs, tlen, idxarr, tot, mel_out);
    gemm_fused<0><<<256, 512, 0, stream>>>(xpad, w1t, b1, g1, be1,
                                           nullptr, nullptr, nullptr, h1pad, nullptr);
    gemm_fused<1><<<256, 512, 0, stream>>>(h1pad, w2t, b2, g2, be2,
                                           lw, lb, tlen, nullptr, pred_out);
    gather_kernel<<<B_ * LMAX_ / 4, 256, 0, stream>>>(batch, idxarr, tot, out);
}

// Round 4
// 499.622 us; speedup vs baseline: 1.0073x; 1.0073x over previous
//
#include <hip/hip_runtime.h>
#include <hip/hip_bf16.h>
#include <stdint.h>

// R7 (466.7us): unfused, BM=128xBN=256, 2 blocks/CU (overlap hides drains).
// R8 (498.1us): fused, BM=64xBN=512 -> B restaged 805MB.
// R9 (CRASH): 160KB static LDS (full pool) -> module/launch abort.
// R10 (503.3us): fused BM=128xBN=512 BK=32 dbuf, but __syncthreads drains
//   vmcnt(0) INCLUDING next tile's loads -> zero net prefetch depth; gemms
//   ~94us each (1 block/CU, nothing hides the drain).
// R11: triple-buffer BK=32 (120KB LDS < 128KB verified cap) + counted-vmcnt
//   pipeline (m201/m218 pattern): STAGE(t+2) -> vmcnt(10) -> barrier ->
//   compute(t) -> barrier.  ~2 iters of load cover, vmcnt never 0 in steady
//   state.  Static named buffers, unroll-by-3 (rule #20).

typedef _Float16 f16;
typedef _Float16 f16x8 __attribute__((ext_vector_type(8)));
typedef float f32x4 __attribute__((ext_vector_type(4)));

#define B_    32
#define T_    1024
#define TP_   1026
#define C_    512
#define LMAX_ 4096
#define KDIM  1536
#define NK    48          // KDIM / 32

// workspace byte offsets (all 256-aligned)
#define XPAD_OFF   0u
#define H1PAD_OFF  33619968u     // 32*1026*512*2
#define W1T_OFF    67239936u
#define W2T_OFF    68812800u
#define TOT_OFF    137494528u
#define IDX_OFF    137495040u

#define AS1C(p) ((const __attribute__((address_space(1))) void*)(p))
#define AS3(p)  ((__attribute__((address_space(3))) void*)(p))

// ---------------------------------------------------------------------------
__global__ __launch_bounds__(256) void prep_pad(const float* __restrict__ batch,
                                                f16* __restrict__ xpad,
                                                f16* __restrict__ h1pad) {
    int row = blockIdx.x * 4 + (threadIdx.x >> 6);   // 0 .. B_*TP_-1
    int lane = threadIdx.x & 63;
    int b = row / TP_, tt = row % TP_;
    size_t dsto = (size_t)row * C_ + lane * 8;
    if (tt == 0 || tt == TP_ - 1) {
        f16x8 z = {};
        *(f16x8*)(xpad + dsto) = z;
        *(f16x8*)(h1pad + dsto) = z;
    } else {
        const float* src = batch + ((size_t)(b * T_ + tt - 1)) * C_ + lane * 8;
        float4 v0 = ((const float4*)src)[0];
        float4 v1 = ((const float4*)src)[1];
        f16x8 h;
        h[0] = (f16)v0.x; h[1] = (f16)v0.y; h[2] = (f16)v0.z; h[3] = (f16)v0.w;
        h[4] = (f16)v1.x; h[5] = (f16)v1.y; h[6] = (f16)v1.z; h[7] = (f16)v1.w;
        *(f16x8*)(xpad + dsto) = h;
    }
}

// ---------------------------------------------------------------------------
__global__ __launch_bounds__(256) void prep_w(const float* __restrict__ w1,
                                              const float* __restrict__ w2,
                                              f16* __restrict__ w1t,
                                              f16* __restrict__ w2t) {
    int o = blockIdx.x;
    const float* w = blockIdx.y ? w2 : w1;
    f16* wt = blockIdx.y ? w2t : w1t;
    for (int j = threadIdx.x; j < KDIM; j += 256) {
        int tap = j >> 9, i = j & 511;
        wt[(size_t)o * KDIM + j] = (f16)w[(size_t)o * KDIM + i * 3 + tap];
    }
}

// ---------------------------------------------------------------------------
__global__ __launch_bounds__(1024) void scan_kernel(const int* __restrict__ dur,
                                                    const int* __restrict__ tlen,
                                                    int* __restrict__ idxarr,
                                                    int* __restrict__ total,
                                                    float* __restrict__ mel_out) {
    int b = blockIdx.x, t = threadIdx.x;
    __shared__ int sd[1024];
    __shared__ int sv[1024];
    int L = tlen[b];
    int valid = (t < L) ? 1 : 0;
    int d = valid ? dur[b * T_ + t] : 0;
    sd[t] = d; sv[t] = valid;
    __syncthreads();
    for (int off = 1; off < 1024; off <<= 1) {
        int x = 0, y = 0;
        if (t >= off) { x = sd[t - off]; y = sv[t - off]; }
        __syncthreads();
        sd[t] += x; sv[t] += y;
        __syncthreads();
    }
    int totd = sd[1023];
    int cur  = (totd == 0) ? sv[t] : sd[t];
    int prev = (t == 0) ? 0 : ((totd == 0) ? sv[t - 1] : sd[t - 1]);
    for (int f = prev; f < cur; f++) idxarr[b * LMAX_ + f] = t;
    if (t == 1023) {
        int tt = (totd == 0) ? sv[1023] : totd;
        total[b] = tt;
        mel_out[b] = (float)tt;
    }
}

// ---------------------------------------------------------------------------
// implicit-GEMM conv fused with LayerNorm epilogue.
// BM=128 x BN=512, 8 waves (2M x 4N), wave tile 64x128 (4x8 frags 16x16x32).
// BK=32, TRIPLE-buffered (120KB LDS), counted-vmcnt pipeline: per iter
//   STAGE(t+2) -> s_waitcnt vmcnt(10) -> s_barrier -> 12 ds_read_b128 +
//   32 MFMA -> s_barrier.  Each tile's 5 loads/wave get ~2 iterations to
//   land; vmcnt never drains to 0 in the main loop (T4).
// LDS row = 32 f16 = 4 granules of 16B; LDS[r][s] holds global granule
// s ^ (r&3) ^ ((r>>2)&3) (involution; pre-swizzled SOURCE + swizzled READ,
// linear dest for global_load_lds; 2-way bank aliasing = free).
template<int EPI>
__global__ __launch_bounds__(512, 2) void gemm_fused(const f16* __restrict__ A,
                                                     const f16* __restrict__ Bw,
                                                     const float* __restrict__ bias,
                                                     const float* __restrict__ g,
                                                     const float* __restrict__ be,
                                                     const float* __restrict__ lw,
                                                     const float* __restrict__ lb,
                                                     const int* __restrict__ tlen,
                                                     f16* __restrict__ hpad,
                                                     float* __restrict__ pred) {
    __shared__ f16 lds_[61440];          // 120 KB: A0|A1|A2|B0|B1|B2
    f16* const A0 = lds_;                // 128*32 = 4096 f16 (8 KB) each
    f16* const A1 = lds_ + 4096;
    f16* const A2 = lds_ + 8192;
    f16* const B0 = lds_ + 12288;        // 512*32 = 16384 f16 (32 KB) each
    f16* const B1 = lds_ + 28672;
    f16* const B2 = lds_ + 45056;
    float* red = (float*)lds_;           // epilogue scratch, aliases A0/A1

    const int tid = threadIdx.x;
    const int lane = tid & 63;
    const int w = tid >> 6;              // 0..7
    const int wm = (w & 1) * 64;         // wave M offset
    const int wn = (w >> 1) * 128;       // wave N offset
    const int m0 = blockIdx.x * 128;
    const int arow0 = (m0 >> 10) * TP_ + (m0 & 1023);

    f32x4 acc[4][8];
#pragma unroll
    for (int i = 0; i < 4; i++)
#pragma unroll
        for (int j = 0; j < 8; j++) acc[i][j] = (f32x4){0.f, 0.f, 0.f, 0.f};

    // swizzle permutation (same value serves staging-source and read-slot)
    const int perm = (lane & 3) ^ ((lane >> 2) & 3) ^ ((lane >> 4) & 3);
    const int base = perm * 8;
    // staging source bases: lane covers row (base + lane>>2), granule perm
    const f16* aB = A + (size_t)(arow0 + w * 16 + (lane >> 2)) * C_ + perm * 8;
    const f16* bB = Bw + (size_t)(w * 16 + (lane >> 2)) * KDIM + perm * 8;

#define STAGE(Ad, Bd, kofs) do {                                              \
        __builtin_amdgcn_global_load_lds(AS1C(aB + (kofs)),                   \
                                         AS3((Ad) + w * 512), 16, 0, 0);      \
        _Pragma("unroll")                                                     \
        for (int j_ = 0; j_ < 4; j_++) {                                      \
            __builtin_amdgcn_global_load_lds(                                 \
                AS1C(bB + (size_t)(128 * j_) * KDIM + (kofs)),                \
                AS3((Bd) + (w + 8 * j_) * 512), 16, 0, 0);                    \
        }                                                                     \
    } while (0)

#define COMPUTE(Ac, Bc) do {                                                  \
        f16x8 af[4], bf[8];                                                   \
        _Pragma("unroll")                                                     \
        for (int mi = 0; mi < 4; mi++)                                        \
            af[mi] = *(const f16x8*)&(Ac)[(wm + mi * 16 + (lane & 15)) * 32 + base]; \
        _Pragma("unroll")                                                     \
        for (int ni = 0; ni < 8; ni++)                                        \
            bf[ni] = *(const f16x8*)&(Bc)[(wn + ni * 16 + (lane & 15)) * 32 + base]; \
        _Pragma("unroll")                                                     \
        for (int mi = 0; mi < 4; mi++)                                        \
            _Pragma("unroll")                                                 \
            for (int ni = 0; ni < 8; ni++)                                    \
                acc[mi][ni] = __builtin_amdgcn_mfma_f32_16x16x32_f16(         \
                    af[mi], bf[ni], acc[mi][ni], 0, 0, 0);                    \
    } while (0)

#define ITER(Ac, Bc, tval, DO_STAGE, An2, Bn2, VMSTR) do {                    \
        if (DO_STAGE) STAGE(An2, Bn2, ((tval) + 2) * 32);                     \
        asm volatile("s_waitcnt " VMSTR ::: "memory");                        \
        __builtin_amdgcn_s_barrier();                                         \
        __builtin_amdgcn_sched_barrier(0);                                    \
        COMPUTE(Ac, Bc);                                                      \
        __builtin_amdgcn_sched_barrier(0);                                    \
        __builtin_amdgcn_s_barrier();                                         \
    } while (0)

    STAGE(A0, B0, 0);                    // prologue: tiles 0,1 in flight
    STAGE(A1, B1, 32);

    for (int tt = 0; tt < NK - 3; tt += 3) {     // tt = 0,3,...,42
        ITER(A0, B0, tt,     1, A2, B2, "vmcnt(10)");
        ITER(A1, B1, tt + 1, 1, A0, B0, "vmcnt(10)");
        ITER(A2, B2, tt + 2, 1, A1, B1, "vmcnt(10)");
    }
    ITER(A0, B0, NK - 3, 1, A2, B2, "vmcnt(10)");   // t=45, stages tile 47
    ITER(A1, B1, NK - 2, 0, A0, B0, "vmcnt(5)");    // t=46
    ITER(A2, B2, NK - 1, 0, A1, B1, "vmcnt(0)");    // t=47

#undef ITER
#undef COMPUTE
#undef STAGE

    // ---------------- fused epilogue ----------------
    const int col = lane & 15;
    const int row4 = (lane >> 4) * 4;
    const int nw = w >> 1;               // N-wave index 0..3

    float bn[8];
#pragma unroll
    for (int ni = 0; ni < 8; ni++) bn[ni] = bias[wn + ni * 16 + col];
    float s_[4][4], q_[4][4];
#pragma unroll
    for (int mi = 0; mi < 4; mi++)
#pragma unroll
        for (int r = 0; r < 4; r++) { s_[mi][r] = 0.f; q_[mi][r] = 0.f; }
#pragma unroll
    for (int mi = 0; mi < 4; mi++)
#pragma unroll
        for (int ni = 0; ni < 8; ni++)
#pragma unroll
            for (int r = 0; r < 4; r++) {
                float v = acc[mi][ni][r] + bn[ni];
                v = v > 0.f ? v : 0.f;
                acc[mi][ni][r] = v;
                s_[mi][r] += v;
                q_[mi][r] += v * v;
            }
    // reduce across the 16 col-lanes (same rows live at same lane>>4)
#pragma unroll
    for (int m = 8; m; m >>= 1)
#pragma unroll
        for (int mi = 0; mi < 4; mi++)
#pragma unroll
            for (int r = 0; r < 4; r++) {
                s_[mi][r] += __shfl_xor(s_[mi][r], m, 64);
                q_[mi][r] += __shfl_xor(q_[mi][r], m, 64);
            }
    // cross-wave reduce via LDS (4 N-wave groups hold disjoint col ranges)
    if (col == 0) {
#pragma unroll
        for (int mi = 0; mi < 4; mi++)
#pragma unroll
            for (int r = 0; r < 4; r++) {
                int row = wm + mi * 16 + row4 + r;     // 0..127
                red[(nw * 128 + row) * 2]     = s_[mi][r];
                red[(nw * 128 + row) * 2 + 1] = q_[mi][r];
            }
    }
    __syncthreads();
    float mu_[4][4], rs_[4][4];
#pragma unroll
    for (int mi = 0; mi < 4; mi++)
#pragma unroll
        for (int r = 0; r < 4; r++) {
            int row = wm + mi * 16 + row4 + r;
            float S = red[row * 2]             + red[(128 + row) * 2]
                    + red[(256 + row) * 2]     + red[(384 + row) * 2];
            float Q = red[row * 2 + 1]         + red[(128 + row) * 2 + 1]
                    + red[(256 + row) * 2 + 1] + red[(384 + row) * 2 + 1];
            float mu = S * (1.f / 512.f);
            float x = Q * (1.f / 512.f) - mu * mu + 1e-5f;
            float rs = rsqrtf(x);
            rs = rs * (1.5f - 0.5f * x * rs * rs);   // Newton refine
            mu_[mi][r] = mu; rs_[mi][r] = rs;
        }

    if (EPI == 0) {
        // LN -> f16 hpad at (b, t+1)
        const int bb = m0 >> 10, t0 = m0 & 1023;
        f16* hbase = hpad + ((size_t)(bb * TP_ + t0 + 1)) * C_;
#pragma unroll
        for (int ni = 0; ni < 8; ni++) {
            int n = wn + ni * 16 + col;
            float gv = g[n], ev = be[n];
#pragma unroll
            for (int mi = 0; mi < 4; mi++)
#pragma unroll
                for (int r = 0; r < 4; r++) {
                    int lm = wm + mi * 16 + row4 + r;
                    float v = (acc[mi][ni][r] - mu_[mi][r]) * rs_[mi][r] * gv + ev;
                    hbase[(size_t)lm * C_ + n] = (f16)v;
                }
        }
    } else {
        // LN + Linear head -> pred[m], masked by token length
        float p_[4][4];
#pragma unroll
        for (int mi = 0; mi < 4; mi++)
#pragma unroll
            for (int r = 0; r < 4; r++) p_[mi][r] = 0.f;
#pragma unroll
        for (int ni = 0; ni < 8; ni++) {
            int n = wn + ni * 16 + col;
            float gv = g[n], ev = be[n], wv = lw[n];
#pragma unroll
            for (int mi = 0; mi < 4; mi++)
#pragma unroll
                for (int r = 0; r < 4; r++)
                    p_[mi][r] += ((acc[mi][ni][r] - mu_[mi][r]) * rs_[mi][r] * gv + ev) * wv;
        }
#pragma unroll
        for (int m = 8; m; m >>= 1)
#pragma unroll
            for (int mi = 0; mi < 4; mi++)
#pragma unroll
                for (int r = 0; r < 4; r++)
                    p_[mi][r] += __shfl_xor(p_[mi][r], m, 64);
        __syncthreads();   // all red[] stat reads complete before reuse
        if (col == 0) {
#pragma unroll
            for (int mi = 0; mi < 4; mi++)
#pragma unroll
                for (int r = 0; r < 4; r++)
                    red[nw * 128 + wm + mi * 16 + row4 + r] = p_[mi][r];
        }
        __syncthreads();
        if (tid < 128) {
            int m = m0 + tid;
            float p = red[tid] + red[128 + tid] + red[256 + tid] + red[384 + tid];
            int bb = m >> 10, t = m & 1023;
            pred[m] = (t < tlen[bb]) ? (p + lb[0]) : 0.f;
        }
    }
}

// ---------------------------------------------------------------------------
__global__ __launch_bounds__(256) void gather_kernel(const float* __restrict__ batch,
                                                     const int* __restrict__ idxarr,
                                                     const int* __restrict__ total,
                                                     float* __restrict__ out) {
    int gw = blockIdx.x * 4 + (threadIdx.x >> 6);  // 0 .. B_*LMAX_-1
    int lane = threadIdx.x & 63;
    int b = gw >> 12;
    int l = gw & (LMAX_ - 1);
    int tot = total[b];
    float4* dst = (float4*)(out + ((size_t)b * LMAX_ + l) * C_);
    if (l < tot) {
        int idx = idxarr[gw];
        const float4* src = (const float4*)(batch + ((size_t)b * T_ + idx) * C_);
        dst[lane] = src[lane];
        dst[lane + 64] = src[lane + 64];
    } else {
        float4 z = {0.f, 0.f, 0.f, 0.f};
        dst[lane] = z;
        dst[lane + 64] = z;
    }
}

// ---------------------------------------------------------------------------
extern "C" void kernel_launch(void* const* d_in, const int* in_sizes, int n_in,
                              void* d_out, int out_size, void* d_ws, size_t ws_size,
                              hipStream_t stream) {
    const float* batch = (const float*)d_in[0];
    const int* tlen    = (const int*)d_in[1];
    const int* durs    = (const int*)d_in[3];
    const float* w1  = (const float*)d_in[4];
    const float* b1  = (const float*)d_in[5];
    const float* g1  = (const float*)d_in[6];
    const float* be1 = (const float*)d_in[7];
    const float* w2  = (const float*)d_in[8];
    const float* b2  = (const float*)d_in[9];
    const float* g2  = (const float*)d_in[10];
    const float* be2 = (const float*)d_in[11];
    const float* lw  = (const float*)d_in[12];
    const float* lb  = (const float*)d_in[13];

    float* out      = (float*)d_out;
    float* mel_out  = out + (size_t)B_ * LMAX_ * C_;
    float* pred_out = mel_out + B_;

    char* ws    = (char*)d_ws;
    f16* xpad   = (f16*)(ws + XPAD_OFF);
    f16* h1pad  = (f16*)(ws + H1PAD_OFF);
    f16* w1t    = (f16*)(ws + W1T_OFF);
    f16* w2t    = (f16*)(ws + W2T_OFF);
    int* tot    = (int*)(ws + TOT_OFF);
    int* idxarr = (int*)(ws + IDX_OFF);

    prep_pad<<<B_ * TP_ / 4, 256, 0, stream>>>(batch, xpad, h1pad);
    prep_w<<<dim3(512, 2), 256, 0, stream>>>(w1, w2, w1t, w2t);
    scan_kernel<<<B_, 1024, 0, stream>>>(durs, tlen, idxarr, tot, mel_out);
    gemm_fused<0><<<256, 512, 0, stream>>>(xpad, w1t, b1, g1, be1,
                                           nullptr, nullptr, nullptr, h1pad, nullptr);
    gemm_fused<1><<<256, 512, 0, stream>>>(h1pad, w2t, b2, g2, be2,
                                           lw, lb, tlen, nullptr, pred_out);
    gather_kernel<<<B_ * LMAX_ / 4, 256, 0, stream>>>(batch, idxarr, tot, out);
}

// Round 5
// 462.096 us; speedup vs baseline: 1.0891x; 1.0812x over previous
//
#include <hip/hip_runtime.h>
#include <hip/hip_bf16.h>
#include <stdint.h>

// R7 (466.7us): unfused, BM=128xBN=256, 2 blocks/CU (overlap hides drains).
// R8/R10/R11 (~500us): every fused BN=512/block geometry -> 1 block/CU ->
//   barrier-locked waves, gemms ~92us.  Lesson: keep R7's 2-blocks/CU gemm.
// R12: R7 gemm/ln/gather verbatim.  gemm2 = R7 gemm + partial-stats epilogue:
//   per row emits (S, Q, U=sum v*g*lw) over its 256 cols, NO Y write (kills
//   32MB write + 128 scalar stores/thread + the 32MB-read ln2pred kernel).
//   finalize2: pred = rs*(U - mu*K1) + K2 + lb  (K1=sum g*lw, K2=sum be*lw,
//   computed in prep_w block 0).

typedef _Float16 f16;
typedef _Float16 f16x8 __attribute__((ext_vector_type(8)));
typedef float f32x4 __attribute__((ext_vector_type(4)));

#define B_    32
#define T_    1024
#define TP_   1026
#define C_    512
#define LMAX_ 4096
#define KDIM  1536

// workspace byte offsets (all 256-aligned)
#define XPAD_OFF   0u
#define H1PAD_OFF  33619968u     // 32*1026*512*2
#define W1T_OFF    67239936u
#define W2T_OFF    68812800u
#define YWS_OFF    70385664u     // f16, 32 MB
#define TOT_OFF    137494528u
#define IDX_OFF    137495040u    // + 32*4096*4 = ends 138019328
#define GWL_OFF    138019328u    // 512 f32
#define K12_OFF    138021376u    // 2 f32 (256-pad)
#define STAT2_OFF  138021888u    // 32768*2 float4 = 1 MB

#define AS1C(p) ((const __attribute__((address_space(1))) void*)(p))
#define AS3(p)  ((__attribute__((address_space(3))) void*)(p))

// ---------------------------------------------------------------------------
__global__ __launch_bounds__(256) void prep_pad(const float* __restrict__ batch,
                                                f16* __restrict__ xpad,
                                                f16* __restrict__ h1pad) {
    int row = blockIdx.x * 4 + (threadIdx.x >> 6);   // 0 .. B_*TP_-1
    int lane = threadIdx.x & 63;
    int b = row / TP_, tt = row % TP_;
    size_t dsto = (size_t)row * C_ + lane * 8;
    if (tt == 0 || tt == TP_ - 1) {
        f16x8 z = {};
        *(f16x8*)(xpad + dsto) = z;
        *(f16x8*)(h1pad + dsto) = z;
    } else {
        const float* src = batch + ((size_t)(b * T_ + tt - 1)) * C_ + lane * 8;
        float4 v0 = ((const float4*)src)[0];
        float4 v1 = ((const float4*)src)[1];
        f16x8 h;
        h[0] = (f16)v0.x; h[1] = (f16)v0.y; h[2] = (f16)v0.z; h[3] = (f16)v0.w;
        h[4] = (f16)v1.x; h[5] = (f16)v1.y; h[6] = (f16)v1.z; h[7] = (f16)v1.w;
        *(f16x8*)(xpad + dsto) = h;
    }
}

// ---------------------------------------------------------------------------
// prep weights + (block 0,0) gwl[c]=g2[c]*lw[c], K1=sum gwl, K2=sum be2*lw.
__global__ __launch_bounds__(256) void prep_w(const float* __restrict__ w1,
                                              const float* __restrict__ w2,
                                              f16* __restrict__ w1t,
                                              f16* __restrict__ w2t,
                                              const float* __restrict__ g2,
                                              const float* __restrict__ be2,
                                              const float* __restrict__ lw,
                                              float* __restrict__ gwl,
                                              float* __restrict__ k12) {
    int o = blockIdx.x;
    const float* w = blockIdx.y ? w2 : w1;
    f16* wt = blockIdx.y ? w2t : w1t;
    for (int j = threadIdx.x; j < KDIM; j += 256) {
        int tap = j >> 9, i = j & 511;
        wt[(size_t)o * KDIM + j] = (f16)w[(size_t)o * KDIM + i * 3 + tap];
    }
    if (blockIdx.x == 0 && blockIdx.y == 0) {
        __shared__ float rk[4][2];
        float k1 = 0.f, k2 = 0.f;
        for (int c = threadIdx.x; c < C_; c += 256) {
            float gw_ = g2[c] * lw[c];
            gwl[c] = gw_;
            k1 += gw_;
            k2 += be2[c] * lw[c];
        }
#pragma unroll
        for (int m = 32; m; m >>= 1) {
            k1 += __shfl_xor(k1, m, 64);
            k2 += __shfl_xor(k2, m, 64);
        }
        if ((threadIdx.x & 63) == 0) {
            rk[threadIdx.x >> 6][0] = k1;
            rk[threadIdx.x >> 6][1] = k2;
        }
        __syncthreads();
        if (threadIdx.x == 0) {
            k12[0] = rk[0][0] + rk[1][0] + rk[2][0] + rk[3][0];
            k12[1] = rk[0][1] + rk[1][1] + rk[2][1] + rk[3][1];
        }
    }
}

// ---------------------------------------------------------------------------
__global__ __launch_bounds__(1024) void scan_kernel(const int* __restrict__ dur,
                                                    const int* __restrict__ tlen,
                                                    int* __restrict__ idxarr,
                                                    int* __restrict__ total,
                                                    float* __restrict__ mel_out) {
    int b = blockIdx.x, t = threadIdx.x;
    __shared__ int sd[1024];
    __shared__ int sv[1024];
    int L = tlen[b];
    int valid = (t < L) ? 1 : 0;
    int d = valid ? dur[b * T_ + t] : 0;
    sd[t] = d; sv[t] = valid;
    __syncthreads();
    for (int off = 1; off < 1024; off <<= 1) {
        int x = 0, y = 0;
        if (t >= off) { x = sd[t - off]; y = sv[t - off]; }
        __syncthreads();
        sd[t] += x; sv[t] += y;
        __syncthreads();
    }
    int totd = sd[1023];
    int cur  = (totd == 0) ? sv[t] : sd[t];
    int prev = (t == 0) ? 0 : ((totd == 0) ? sv[t - 1] : sd[t - 1]);
    for (int f = prev; f < cur; f++) idxarr[b * LMAX_ + f] = t;
    if (t == 1023) {
        int tt = (totd == 0) ? sv[1023] : totd;
        total[b] = tt;
        mel_out[b] = (float)tt;
    }
}

// ---------------------------------------------------------------------------
// implicit-GEMM conv (R7-verified structure): BM=128 x BN=256, 4 waves, wave
// tile 64x128 (4x8 frags of 16x16x32), BK=64, 48KB LDS -> 2 blocks/CU.
// XOR granule swizzle: LDS[r][s] holds global granule s^(r&7).
// EPI=0: Y = relu(A@Bw^T + bias)  (R7 verbatim, feeds ln_kernel)
// EPI=1: no Y write; per row emit partials (S=sum v, Q=sum v^2, U=sum v*gwl)
//        over this block's 256 cols -> stats[m][nblk] (float4).
template<int EPI>
__global__ __launch_bounds__(256, 2) void gemm_k(const f16* __restrict__ A,
                                                 const f16* __restrict__ Bw,
                                                 const float* __restrict__ bias,
                                                 f16* __restrict__ Y,
                                                 const float* __restrict__ gwl,
                                                 float4* __restrict__ stats) {
    __shared__ f16 As[128 * 64];   // 16 KB
    __shared__ f16 Bs[256 * 64];   // 32 KB
    const int tid = threadIdx.x;
    const int lane = tid & 63;
    const int w = tid >> 6;        // 0..3
    const int m0 = blockIdx.x * 128;
    const int n0 = blockIdx.y * 256;
    const int arow0 = (m0 >> 10) * TP_ + (m0 & 1023);
    const int wm = (w & 1) * 64;
    const int wn = (w >> 1) * 128;

    f32x4 acc[4][8];
#pragma unroll
    for (int i = 0; i < 4; i++)
#pragma unroll
        for (int j = 0; j < 8; j++) acc[i][j] = (f32x4){0.f, 0.f, 0.f, 0.f};

    const int lrow = lane >> 3;                  // 0..7
    const int gran = (lane & 7) ^ lrow;          // swizzled source granule
    const f16* aB = A + (size_t)(arow0 + lrow) * C_ + gran * 8;
    const f16* bB = Bw + (size_t)(n0 + lrow) * KDIM + gran * 8;

    for (int kk = 0; kk < KDIM; kk += 64) {
        __syncthreads();
#pragma unroll
        for (int i = 0; i < 4; i++) {           // A: 16 wave-loads / 4 waves
            const int rb = (w + i * 4) * 8;
            __builtin_amdgcn_global_load_lds(AS1C(aB + (size_t)rb * C_ + kk),
                                             AS3(&As[rb * 64]), 16, 0, 0);
        }
#pragma unroll
        for (int j = 0; j < 8; j++) {           // B: 32 wave-loads / 4 waves
            const int rb = (w + j * 4) * 8;
            __builtin_amdgcn_global_load_lds(AS1C(bB + (size_t)rb * KDIM + kk),
                                             AS3(&Bs[rb * 64]), 16, 0, 0);
        }
        __syncthreads();   // drains vmcnt -> LDS tiles complete
#pragma unroll
        for (int ks = 0; ks < 2; ks++) {
            const int sl = ((ks << 2) + (lane >> 4)) ^ (lane & 7);
            f16x8 af[4], bf[8];
#pragma unroll
            for (int mi = 0; mi < 4; mi++)
                af[mi] = *(const f16x8*)&As[(wm + mi * 16 + (lane & 15)) * 64 + sl * 8];
#pragma unroll
            for (int ni = 0; ni < 8; ni++)
                bf[ni] = *(const f16x8*)&Bs[(wn + ni * 16 + (lane & 15)) * 64 + sl * 8];
#pragma unroll
            for (int mi = 0; mi < 4; mi++)
#pragma unroll
                for (int ni = 0; ni < 8; ni++)
                    acc[mi][ni] = __builtin_amdgcn_mfma_f32_16x16x32_f16(
                        af[mi], bf[ni], acc[mi][ni], 0, 0, 0);
        }
    }

    const int col = lane & 15;
    const int row4 = (lane >> 4) * 4;

    if (EPI == 0) {
        // R7 verbatim: bias + relu -> Y (f16)
#pragma unroll
        for (int ni = 0; ni < 8; ni++) {
            int n = n0 + wn + ni * 16 + col;
            float bn = bias[n];
#pragma unroll
            for (int mi = 0; mi < 4; mi++) {
#pragma unroll
                for (int r = 0; r < 4; r++) {
                    int m = m0 + wm + mi * 16 + row4 + r;
                    float v = acc[mi][ni][r] + bn;
                    Y[(size_t)m * C_ + n] = (f16)(v > 0.f ? v : 0.f);
                }
            }
        }
    } else {
        // partial stats over this block's 256 cols
        float bn[8], gw[8];
#pragma unroll
        for (int ni = 0; ni < 8; ni++) {
            int n = n0 + wn + ni * 16 + col;
            bn[ni] = bias[n];
            gw[ni] = gwl[n];
        }
        float s_[4][4], q_[4][4], u_[4][4];
#pragma unroll
        for (int mi = 0; mi < 4; mi++)
#pragma unroll
            for (int r = 0; r < 4; r++) { s_[mi][r] = 0.f; q_[mi][r] = 0.f; u_[mi][r] = 0.f; }
#pragma unroll
        for (int mi = 0; mi < 4; mi++)
#pragma unroll
            for (int ni = 0; ni < 8; ni++)
#pragma unroll
                for (int r = 0; r < 4; r++) {
                    float v = acc[mi][ni][r] + bn[ni];
                    v = v > 0.f ? v : 0.f;
                    s_[mi][r] += v;
                    q_[mi][r] += v * v;
                    u_[mi][r] += v * gw[ni];
                }
        // reduce across the 16 col-lanes
#pragma unroll
        for (int m = 8; m; m >>= 1)
#pragma unroll
            for (int mi = 0; mi < 4; mi++)
#pragma unroll
                for (int r = 0; r < 4; r++) {
                    s_[mi][r] += __shfl_xor(s_[mi][r], m, 64);
                    q_[mi][r] += __shfl_xor(q_[mi][r], m, 64);
                    u_[mi][r] += __shfl_xor(u_[mi][r], m, 64);
                }
        // cross-wave combine (waves w and w+2 share rows, different cols)
        __syncthreads();                       // main-loop LDS reads done
        float* red = (float*)As;               // [2][128][3] = 3 KB
        if (col == 0) {
#pragma unroll
            for (int mi = 0; mi < 4; mi++)
#pragma unroll
                for (int r = 0; r < 4; r++) {
                    int row = wm + mi * 16 + row4 + r;   // 0..127
                    int idx = ((w >> 1) * 128 + row) * 3;
                    red[idx]     = s_[mi][r];
                    red[idx + 1] = q_[mi][r];
                    red[idx + 2] = u_[mi][r];
                }
        }
        __syncthreads();
        if (tid < 128) {
            float S = red[tid * 3]     + red[(128 + tid) * 3];
            float Q = red[tid * 3 + 1] + red[(128 + tid) * 3 + 1];
            float U = red[tid * 3 + 2] + red[(128 + tid) * 3 + 2];
            stats[(size_t)(m0 + tid) * 2 + blockIdx.y] = (float4){S, Q, U, 0.f};
        }
    }
}

// ---------------------------------------------------------------------------
// LayerNorm over C=512 (input f16), wave per row, write fp16 into h1pad.
__global__ __launch_bounds__(256) void ln_kernel(const f16* __restrict__ Y,
                                                 const float* __restrict__ g,
                                                 const float* __restrict__ be,
                                                 f16* __restrict__ hpad) {
    int row = blockIdx.x * 4 + (threadIdx.x >> 6);
    int lane = threadIdx.x & 63;
    f16x8 yv = *(const f16x8*)(Y + (size_t)row * C_ + lane * 8);
    float v[8];
#pragma unroll
    for (int i = 0; i < 8; i++) v[i] = (float)yv[i];
    float s = 0.f, q = 0.f;
#pragma unroll
    for (int i = 0; i < 8; i++) { s += v[i]; q += v[i] * v[i]; }
#pragma unroll
    for (int m = 32; m; m >>= 1) { s += __shfl_xor(s, m, 64); q += __shfl_xor(q, m, 64); }
    float mu = s * (1.f / 512.f);
    float x = q * (1.f / 512.f) - mu * mu + 1e-5f;
    float rs = rsqrtf(x);
    rs = rs * (1.5f - 0.5f * x * rs * rs);   // Newton refine
    const float4 g0 = ((const float4*)g)[lane * 2], g1 = ((const float4*)g)[lane * 2 + 1];
    const float4 e0 = ((const float4*)be)[lane * 2], e1 = ((const float4*)be)[lane * 2 + 1];
    f16x8 h;
    h[0] = (f16)((v[0] - mu) * rs * g0.x + e0.x);
    h[1] = (f16)((v[1] - mu) * rs * g0.y + e0.y);
    h[2] = (f16)((v[2] - mu) * rs * g0.z + e0.z);
    h[3] = (f16)((v[3] - mu) * rs * g0.w + e0.w);
    h[4] = (f16)((v[4] - mu) * rs * g1.x + e1.x);
    h[5] = (f16)((v[5] - mu) * rs * g1.y + e1.y);
    h[6] = (f16)((v[6] - mu) * rs * g1.z + e1.z);
    h[7] = (f16)((v[7] - mu) * rs * g1.w + e1.w);
    int b = row >> 10, t = row & 1023;
    *(f16x8*)(hpad + ((size_t)(b * TP_ + t + 1)) * C_ + lane * 8) = h;
}

// ---------------------------------------------------------------------------
// finalize: pred[m] = mask * (rs*(U - mu*K1) + K2 + lb)
__global__ __launch_bounds__(256) void finalize2(const float4* __restrict__ stats,
                                                 const float* __restrict__ k12,
                                                 const float* __restrict__ lb,
                                                 const int* __restrict__ tlen,
                                                 float* __restrict__ pred) {
    int m = blockIdx.x * 256 + threadIdx.x;    // grid 128 -> 32768
    float4 a = stats[(size_t)m * 2];
    float4 b = stats[(size_t)m * 2 + 1];
    float S = a.x + b.x, Q = a.y + b.y, U = a.z + b.z;
    float mu = S * (1.f / 512.f);
    float x = Q * (1.f / 512.f) - mu * mu + 1e-5f;
    float rs = rsqrtf(x);
    rs = rs * (1.5f - 0.5f * x * rs * rs);
    float p = rs * (U - mu * k12[0]) + k12[1] + lb[0];
    int bb = m >> 10, t = m & 1023;
    pred[m] = (t < tlen[bb]) ? p : 0.f;
}

// ---------------------------------------------------------------------------
__global__ __launch_bounds__(256) void gather_kernel(const float* __restrict__ batch,
                                                     const int* __restrict__ idxarr,
                                                     const int* __restrict__ total,
                                                     float* __restrict__ out) {
    int gw = blockIdx.x * 4 + (threadIdx.x >> 6);  // 0 .. B_*LMAX_-1
    int lane = threadIdx.x & 63;
    int b = gw >> 12;
    int l = gw & (LMAX_ - 1);
    int tot = total[b];
    float4* dst = (float4*)(out + ((size_t)b * LMAX_ + l) * C_);
    if (l < tot) {
        int idx = idxarr[gw];
        const float4* src = (const float4*)(batch + ((size_t)b * T_ + idx) * C_);
        dst[lane] = src[lane];
        dst[lane + 64] = src[lane + 64];
    } else {
        float4 z = {0.f, 0.f, 0.f, 0.f};
        dst[lane] = z;
        dst[lane + 64] = z;
    }
}

// ---------------------------------------------------------------------------
extern "C" void kernel_launch(void* const* d_in, const int* in_sizes, int n_in,
                              void* d_out, int out_size, void* d_ws, size_t ws_size,
                              hipStream_t stream) {
    const float* batch = (const float*)d_in[0];
    const int* tlen    = (const int*)d_in[1];
    const int* durs    = (const int*)d_in[3];
    const float* w1  = (const float*)d_in[4];
    const float* b1  = (const float*)d_in[5];
    const float* g1  = (const float*)d_in[6];
    const float* be1 = (const float*)d_in[7];
    const float* w2  = (const float*)d_in[8];
    const float* b2  = (const float*)d_in[9];
    const float* g2  = (const float*)d_in[10];
    const float* be2 = (const float*)d_in[11];
    const float* lw  = (const float*)d_in[12];
    const float* lb  = (const float*)d_in[13];

    float* out      = (float*)d_out;
    float* mel_out  = out + (size_t)B_ * LMAX_ * C_;
    float* pred_out = mel_out + B_;

    char* ws    = (char*)d_ws;
    f16* xpad   = (f16*)(ws + XPAD_OFF);
    f16* h1pad  = (f16*)(ws + H1PAD_OFF);
    f16* w1t    = (f16*)(ws + W1T_OFF);
    f16* w2t    = (f16*)(ws + W2T_OFF);
    f16* yws    = (f16*)(ws + YWS_OFF);
    int* tot    = (int*)(ws + TOT_OFF);
    int* idxarr = (int*)(ws + IDX_OFF);
    float* gwl  = (float*)(ws + GWL_OFF);
    float* k12  = (float*)(ws + K12_OFF);
    float4* st2 = (float4*)(ws + STAT2_OFF);

    prep_pad<<<B_ * TP_ / 4, 256, 0, stream>>>(batch, xpad, h1pad);
    prep_w<<<dim3(512, 2), 256, 0, stream>>>(w1, w2, w1t, w2t, g2, be2, lw, gwl, k12);
    scan_kernel<<<B_, 1024, 0, stream>>>(durs, tlen, idxarr, tot, mel_out);
    gemm_k<0><<<dim3(256, 2), 256, 0, stream>>>(xpad, w1t, b1, yws, nullptr, nullptr);
    ln_kernel<<<8192, 256, 0, stream>>>(yws, g1, be1, h1pad);
    gemm_k<1><<<dim3(256, 2), 256, 0, stream>>>(h1pad, w2t, b2, nullptr, gwl, st2);
    finalize2<<<128, 256, 0, stream>>>(st2, k12, lb, tlen, pred_out);
    gather_kernel<<<B_ * LMAX_ / 4, 256, 0, stream>>>(batch, idxarr, tot, out);
}

// Round 6
// 450.246 us; speedup vs baseline: 1.1178x; 1.0263x over previous
//
#include <hip/hip_runtime.h>
#include <hip/hip_bf16.h>
#include <stdint.h>

// R7 (466.7us): unfused baseline.  R8/R10/R11 (~500us): fused-LN geometries
//   at 1 block/CU all fail -> keep 2-blocks/CU gemm.
// R12 (462.1us): gemm2 emits per-row partial stats (S,Q,U), no Y write;
//   finalize2 computes pred.  NEW BEST.
// R13: kill serialization + dead work.  (a) fused_prep merges
//   prep_pad+prep_w+scan+k12 (were 3 serial dispatches ~42us -> ~27us);
//   (b) ln skips rows t>tlen (queued kernel -> real win); (c) prep_pad
//   skips rows tt>tlen+130; (d) gather+finalize merged; (e) gemm blocks
//   early-exit when fully dead (t0>tlen / t0>=tlen).  Live-data outputs
//   are bit-identical to R12; dead rows produce garbage that is masked
//   (pred select) or never read (verified chain: live gemm2 rows read
//   h1 rows <= tlen <- ln t<=tlen <- gemm1 blocks t0<=tlen <- xpad
//   rows <= tlen+130).

typedef _Float16 f16;
typedef _Float16 f16x8 __attribute__((ext_vector_type(8)));
typedef float f32x4 __attribute__((ext_vector_type(4)));

#define B_    32
#define T_    1024
#define TP_   1026
#define C_    512
#define LMAX_ 4096
#define KDIM  1536

// workspace byte offsets (all 256-aligned)
#define XPAD_OFF   0u
#define H1PAD_OFF  33619968u     // 32*1026*512*2
#define W1T_OFF    67239936u
#define W2T_OFF    68812800u
#define YWS_OFF    70385664u     // f16, 32 MB
#define TOT_OFF    137494528u
#define IDX_OFF    137495040u    // + 32*4096*4 = ends 138019328
#define GWL_OFF    138019328u    // 512 f32
#define K12_OFF    138021376u    // 2 f32 (256-pad)
#define STAT2_OFF  138021888u    // 32768*2 float4 = 1 MB

#define AS1C(p) ((const __attribute__((address_space(1))) void*)(p))
#define AS3(p)  ((__attribute__((address_space(3))) void*)(p))

// fused_prep grid partition (1024 threads/block)
#define PP_BLOCKS   2052         // prep_pad: 32832 rows / 16 per block
#define PW_BLOCKS   256          // prep_w: 1024 units / 4 per block
#define SCAN_BLOCKS 32

// ---------------------------------------------------------------------------
// One dispatch running four independent prep stages concurrently:
//   [0,2052)      prep_pad   (16 rows/block, wave per row)
//   [2052,2308)   prep_w     (4 (o,which) units/block, 256 thr each)
//   [2308,2340)   scan       (1 batch/block, 1024 thr)
//   [2340]        gwl + K1/K2
__global__ __launch_bounds__(1024) void fused_prep(
        const float* __restrict__ batch, f16* __restrict__ xpad,
        f16* __restrict__ h1pad, const int* __restrict__ tlen,
        const float* __restrict__ w1, const float* __restrict__ w2,
        f16* __restrict__ w1t, f16* __restrict__ w2t,
        const float* __restrict__ g2, const float* __restrict__ be2,
        const float* __restrict__ lw, float* __restrict__ gwl,
        float* __restrict__ k12,
        const int* __restrict__ dur, int* __restrict__ idxarr,
        int* __restrict__ total, float* __restrict__ mel_out) {
    __shared__ int sd[1024];
    __shared__ int sv[1024];
    __shared__ float rk[8][2];
    const int bid = blockIdx.x;
    const int tid = threadIdx.x;

    if (bid < PP_BLOCKS) {                       // ---- prep_pad ----
        int row = bid * 16 + (tid >> 6);         // 0 .. 32831
        int lane = tid & 63;
        int b = row / TP_, tt = row % TP_;
        size_t dsto = (size_t)row * C_ + lane * 8;
        if (tt == 0 || tt == TP_ - 1) {
            f16x8 z = {};
            *(f16x8*)(xpad + dsto) = z;
            *(f16x8*)(h1pad + dsto) = z;
        } else if (tt <= tlen[b] + 130) {        // dead rows stay poisoned
            const float* src = batch + ((size_t)(b * T_ + tt - 1)) * C_ + lane * 8;
            float4 v0 = ((const float4*)src)[0];
            float4 v1 = ((const float4*)src)[1];
            f16x8 h;
            h[0] = (f16)v0.x; h[1] = (f16)v0.y; h[2] = (f16)v0.z; h[3] = (f16)v0.w;
            h[4] = (f16)v1.x; h[5] = (f16)v1.y; h[6] = (f16)v1.z; h[7] = (f16)v1.w;
            *(f16x8*)(xpad + dsto) = h;
        }
        return;
    }
    if (bid < PP_BLOCKS + PW_BLOCKS) {           // ---- prep_w ----
        int unit = (bid - PP_BLOCKS) * 4 + (tid >> 8);  // 0..1023
        int o = unit & 511;
        const float* w = (unit >> 9) ? w2 : w1;
        f16* wt = (unit >> 9) ? w2t : w1t;
        int tl = tid & 255;
        for (int j = tl; j < KDIM; j += 256) {
            int tap = j >> 9, i = j & 511;
            wt[(size_t)o * KDIM + j] = (f16)w[(size_t)o * KDIM + i * 3 + tap];
        }
        return;
    }
    if (bid < PP_BLOCKS + PW_BLOCKS + SCAN_BLOCKS) {   // ---- scan ----
        int b = bid - (PP_BLOCKS + PW_BLOCKS);
        int t = tid;
        int L = tlen[b];
        int valid = (t < L) ? 1 : 0;
        int d = valid ? dur[b * T_ + t] : 0;
        sd[t] = d; sv[t] = valid;
        __syncthreads();
        for (int off = 1; off < 1024; off <<= 1) {
            int x = 0, y = 0;
            if (t >= off) { x = sd[t - off]; y = sv[t - off]; }
            __syncthreads();
            sd[t] += x; sv[t] += y;
            __syncthreads();
        }
        int totd = sd[1023];
        int cur  = (totd == 0) ? sv[t] : sd[t];
        int prev = (t == 0) ? 0 : ((totd == 0) ? sv[t - 1] : sd[t - 1]);
        for (int f = prev; f < cur; f++) idxarr[b * LMAX_ + f] = t;
        if (t == 1023) {
            int tt = (totd == 0) ? sv[1023] : totd;
            total[b] = tt;
            mel_out[b] = (float)tt;
        }
        return;
    }
    // ---- gwl + K1/K2 (single block) ----
    {
        float k1 = 0.f, k2 = 0.f;
        if (tid < C_) {
            float gw_ = g2[tid] * lw[tid];
            gwl[tid] = gw_;
            k1 = gw_;
            k2 = be2[tid] * lw[tid];
        }
#pragma unroll
        for (int m = 32; m; m >>= 1) {
            k1 += __shfl_xor(k1, m, 64);
            k2 += __shfl_xor(k2, m, 64);
        }
        int wv = tid >> 6;
        if ((tid & 63) == 0 && wv < 8) { rk[wv][0] = k1; rk[wv][1] = k2; }
        __syncthreads();
        if (tid == 0) {
            float a1 = 0.f, a2 = 0.f;
#pragma unroll
            for (int i = 0; i < 8; i++) { a1 += rk[i][0]; a2 += rk[i][1]; }
            k12[0] = a1; k12[1] = a2;
        }
    }
}

// ---------------------------------------------------------------------------
// implicit-GEMM conv (R7-verified structure): BM=128 x BN=256, 4 waves, wave
// tile 64x128 (4x8 frags of 16x16x32), BK=64, 48KB LDS -> 2 blocks/CU.
// XOR granule swizzle: LDS[r][s] holds global granule s^(r&7).
// Dead-block exit: EPI=0 block dead iff t0 > tlen[b]; EPI=1 iff t0 >= tlen[b].
// EPI=0: Y = relu(A@Bw^T + bias)  (feeds ln_kernel)
// EPI=1: no Y write; per row emit partials (S=sum v, Q=sum v^2, U=sum v*gwl)
//        over this block's 256 cols -> stats[m][nblk] (float4).
template<int EPI>
__global__ __launch_bounds__(256, 2) void gemm_k(const f16* __restrict__ A,
                                                 const f16* __restrict__ Bw,
                                                 const float* __restrict__ bias,
                                                 f16* __restrict__ Y,
                                                 const float* __restrict__ gwl,
                                                 float4* __restrict__ stats,
                                                 const int* __restrict__ tlen) {
    __shared__ f16 As[128 * 64];   // 16 KB
    __shared__ f16 Bs[256 * 64];   // 32 KB
    const int m0 = blockIdx.x * 128;
    {
        const int bb = m0 >> 10, t0 = m0 & 1023;
        const int L = tlen[bb];
        if (EPI == 0 ? (t0 > L) : (t0 >= L)) return;   // block-uniform
    }
    const int tid = threadIdx.x;
    const int lane = tid & 63;
    const int w = tid >> 6;        // 0..3
    const int n0 = blockIdx.y * 256;
    const int arow0 = (m0 >> 10) * TP_ + (m0 & 1023);
    const int wm = (w & 1) * 64;
    const int wn = (w >> 1) * 128;

    f32x4 acc[4][8];
#pragma unroll
    for (int i = 0; i < 4; i++)
#pragma unroll
        for (int j = 0; j < 8; j++) acc[i][j] = (f32x4){0.f, 0.f, 0.f, 0.f};

    const int lrow = lane >> 3;                  // 0..7
    const int gran = (lane & 7) ^ lrow;          // swizzled source granule
    const f16* aB = A + (size_t)(arow0 + lrow) * C_ + gran * 8;
    const f16* bB = Bw + (size_t)(n0 + lrow) * KDIM + gran * 8;

    for (int kk = 0; kk < KDIM; kk += 64) {
        __syncthreads();
#pragma unroll
        for (int i = 0; i < 4; i++) {           // A: 16 wave-loads / 4 waves
            const int rb = (w + i * 4) * 8;
            __builtin_amdgcn_global_load_lds(AS1C(aB + (size_t)rb * C_ + kk),
                                             AS3(&As[rb * 64]), 16, 0, 0);
        }
#pragma unroll
        for (int j = 0; j < 8; j++) {           // B: 32 wave-loads / 4 waves
            const int rb = (w + j * 4) * 8;
            __builtin_amdgcn_global_load_lds(AS1C(bB + (size_t)rb * KDIM + kk),
                                             AS3(&Bs[rb * 64]), 16, 0, 0);
        }
        __syncthreads();   // drains vmcnt -> LDS tiles complete
#pragma unroll
        for (int ks = 0; ks < 2; ks++) {
            const int sl = ((ks << 2) + (lane >> 4)) ^ (lane & 7);
            f16x8 af[4], bf[8];
#pragma unroll
            for (int mi = 0; mi < 4; mi++)
                af[mi] = *(const f16x8*)&As[(wm + mi * 16 + (lane & 15)) * 64 + sl * 8];
#pragma unroll
            for (int ni = 0; ni < 8; ni++)
                bf[ni] = *(const f16x8*)&Bs[(wn + ni * 16 + (lane & 15)) * 64 + sl * 8];
#pragma unroll
            for (int mi = 0; mi < 4; mi++)
#pragma unroll
                for (int ni = 0; ni < 8; ni++)
                    acc[mi][ni] = __builtin_amdgcn_mfma_f32_16x16x32_f16(
                        af[mi], bf[ni], acc[mi][ni], 0, 0, 0);
        }
    }

    const int col = lane & 15;
    const int row4 = (lane >> 4) * 4;

    if (EPI == 0) {
        // bias + relu -> Y (f16)
#pragma unroll
        for (int ni = 0; ni < 8; ni++) {
            int n = n0 + wn + ni * 16 + col;
            float bn = bias[n];
#pragma unroll
            for (int mi = 0; mi < 4; mi++) {
#pragma unroll
                for (int r = 0; r < 4; r++) {
                    int m = m0 + wm + mi * 16 + row4 + r;
                    float v = acc[mi][ni][r] + bn;
                    Y[(size_t)m * C_ + n] = (f16)(v > 0.f ? v : 0.f);
                }
            }
        }
    } else {
        // partial stats over this block's 256 cols
        float bn[8], gw[8];
#pragma unroll
        for (int ni = 0; ni < 8; ni++) {
            int n = n0 + wn + ni * 16 + col;
            bn[ni] = bias[n];
            gw[ni] = gwl[n];
        }
        float s_[4][4], q_[4][4], u_[4][4];
#pragma unroll
        for (int mi = 0; mi < 4; mi++)
#pragma unroll
            for (int r = 0; r < 4; r++) { s_[mi][r] = 0.f; q_[mi][r] = 0.f; u_[mi][r] = 0.f; }
#pragma unroll
        for (int mi = 0; mi < 4; mi++)
#pragma unroll
            for (int ni = 0; ni < 8; ni++)
#pragma unroll
                for (int r = 0; r < 4; r++) {
                    float v = acc[mi][ni][r] + bn[ni];
                    v = v > 0.f ? v : 0.f;
                    s_[mi][r] += v;
                    q_[mi][r] += v * v;
                    u_[mi][r] += v * gw[ni];
                }
        // reduce across the 16 col-lanes
#pragma unroll
        for (int m = 8; m; m >>= 1)
#pragma unroll
            for (int mi = 0; mi < 4; mi++)
#pragma unroll
                for (int r = 0; r < 4; r++) {
                    s_[mi][r] += __shfl_xor(s_[mi][r], m, 64);
                    q_[mi][r] += __shfl_xor(q_[mi][r], m, 64);
                    u_[mi][r] += __shfl_xor(u_[mi][r], m, 64);
                }
        // cross-wave combine (waves w and w+2 share rows, different cols)
        __syncthreads();                       // main-loop LDS reads done
        float* red = (float*)As;               // [2][128][3] = 3 KB
        if (col == 0) {
#pragma unroll
            for (int mi = 0; mi < 4; mi++)
#pragma unroll
                for (int r = 0; r < 4; r++) {
                    int row = wm + mi * 16 + row4 + r;   // 0..127
                    int idx = ((w >> 1) * 128 + row) * 3;
                    red[idx]     = s_[mi][r];
                    red[idx + 1] = q_[mi][r];
                    red[idx + 2] = u_[mi][r];
                }
        }
        __syncthreads();
        if (tid < 128) {
            float S = red[tid * 3]     + red[(128 + tid) * 3];
            float Q = red[tid * 3 + 1] + red[(128 + tid) * 3 + 1];
            float U = red[tid * 3 + 2] + red[(128 + tid) * 3 + 2];
            stats[(size_t)(m0 + tid) * 2 + blockIdx.y] = (float4){S, Q, U, 0.f};
        }
    }
}

// ---------------------------------------------------------------------------
// LayerNorm over C=512 (input f16), wave per row, write fp16 into h1pad.
// Skips rows t > tlen[b] (outputs never read by live gemm2 rows).
__global__ __launch_bounds__(256) void ln_kernel(const f16* __restrict__ Y,
                                                 const float* __restrict__ g,
                                                 const float* __restrict__ be,
                                                 f16* __restrict__ hpad,
                                                 const int* __restrict__ tlen) {
    int row = blockIdx.x * 4 + (threadIdx.x >> 6);
    int lane = threadIdx.x & 63;
    int b = row >> 10, t = row & 1023;
    if (t > tlen[b]) return;                 // wave-uniform
    f16x8 yv = *(const f16x8*)(Y + (size_t)row * C_ + lane * 8);
    float v[8];
#pragma unroll
    for (int i = 0; i < 8; i++) v[i] = (float)yv[i];
    float s = 0.f, q = 0.f;
#pragma unroll
    for (int i = 0; i < 8; i++) { s += v[i]; q += v[i] * v[i]; }
#pragma unroll
    for (int m = 32; m; m >>= 1) { s += __shfl_xor(s, m, 64); q += __shfl_xor(q, m, 64); }
    float mu = s * (1.f / 512.f);
    float x = q * (1.f / 512.f) - mu * mu + 1e-5f;
    float rs = rsqrtf(x);
    rs = rs * (1.5f - 0.5f * x * rs * rs);   // Newton refine
    const float4 g0 = ((const float4*)g)[lane * 2], g1 = ((const float4*)g)[lane * 2 + 1];
    const float4 e0 = ((const float4*)be)[lane * 2], e1 = ((const float4*)be)[lane * 2 + 1];
    f16x8 h;
    h[0] = (f16)((v[0] - mu) * rs * g0.x + e0.x);
    h[1] = (f16)((v[1] - mu) * rs * g0.y + e0.y);
    h[2] = (f16)((v[2] - mu) * rs * g0.z + e0.z);
    h[3] = (f16)((v[3] - mu) * rs * g0.w + e0.w);
    h[4] = (f16)((v[4] - mu) * rs * g1.x + e1.x);
    h[5] = (f16)((v[5] - mu) * rs * g1.y + e1.y);
    h[6] = (f16)((v[6] - mu) * rs * g1.z + e1.z);
    h[7] = (f16)((v[7] - mu) * rs * g1.w + e1.w);
    *(f16x8*)(hpad + ((size_t)(b * TP_ + t + 1)) * C_ + lane * 8) = h;
}

// ---------------------------------------------------------------------------
// merged: [0,32768) regulate gather; [32768,32896) finalize pred.
__global__ __launch_bounds__(256) void gather_fin(const float* __restrict__ batch,
                                                  const int* __restrict__ idxarr,
                                                  const int* __restrict__ total,
                                                  float* __restrict__ out,
                                                  const float4* __restrict__ stats,
                                                  const float* __restrict__ k12,
                                                  const float* __restrict__ lb,
                                                  const int* __restrict__ tlen,
                                                  float* __restrict__ pred) {
    if (blockIdx.x < 32768) {
        int gw = blockIdx.x * 4 + (threadIdx.x >> 6);  // 0 .. B_*LMAX_-1
        int lane = threadIdx.x & 63;
        int b = gw >> 12;
        int l = gw & (LMAX_ - 1);
        int tot = total[b];
        float4* dst = (float4*)(out + ((size_t)b * LMAX_ + l) * C_);
        if (l < tot) {
            int idx = idxarr[gw];
            const float4* src = (const float4*)(batch + ((size_t)b * T_ + idx) * C_);
            dst[lane] = src[lane];
            dst[lane + 64] = src[lane + 64];
        } else {
            float4 z = {0.f, 0.f, 0.f, 0.f};
            dst[lane] = z;
            dst[lane + 64] = z;
        }
    } else {
        int m = (blockIdx.x - 32768) * 256 + threadIdx.x;   // 0..32767
        float4 a = stats[(size_t)m * 2];
        float4 b = stats[(size_t)m * 2 + 1];
        float S = a.x + b.x, Q = a.y + b.y, U = a.z + b.z;
        float mu = S * (1.f / 512.f);
        float x = Q * (1.f / 512.f) - mu * mu + 1e-5f;
        float rs = rsqrtf(x);
        rs = rs * (1.5f - 0.5f * x * rs * rs);
        float p = rs * (U - mu * k12[0]) + k12[1] + lb[0];
        int bb = m >> 10, t = m & 1023;
        pred[m] = (t < tlen[bb]) ? p : 0.f;
    }
}

// ---------------------------------------------------------------------------
extern "C" void kernel_launch(void* const* d_in, const int* in_sizes, int n_in,
                              void* d_out, int out_size, void* d_ws, size_t ws_size,
                              hipStream_t stream) {
    const float* batch = (const float*)d_in[0];
    const int* tlen    = (const int*)d_in[1];
    const int* durs    = (const int*)d_in[3];
    const float* w1  = (const float*)d_in[4];
    const float* b1  = (const float*)d_in[5];
    const float* g1  = (const float*)d_in[6];
    const float* be1 = (const float*)d_in[7];
    const float* w2  = (const float*)d_in[8];
    const float* b2  = (const float*)d_in[9];
    const float* g2  = (const float*)d_in[10];
    const float* be2 = (const float*)d_in[11];
    const float* lw  = (const float*)d_in[12];
    const float* lb  = (const float*)d_in[13];

    float* out      = (float*)d_out;
    float* mel_out  = out + (size_t)B_ * LMAX_ * C_;
    float* pred_out = mel_out + B_;

    char* ws    = (char*)d_ws;
    f16* xpad   = (f16*)(ws + XPAD_OFF);
    f16* h1pad  = (f16*)(ws + H1PAD_OFF);
    f16* w1t    = (f16*)(ws + W1T_OFF);
    f16* w2t    = (f16*)(ws + W2T_OFF);
    f16* yws    = (f16*)(ws + YWS_OFF);
    int* tot    = (int*)(ws + TOT_OFF);
    int* idxarr = (int*)(ws + IDX_OFF);
    float* gwl  = (float*)(ws + GWL_OFF);
    float* k12  = (float*)(ws + K12_OFF);
    float4* st2 = (float4*)(ws + STAT2_OFF);

    fused_prep<<<PP_BLOCKS + PW_BLOCKS + SCAN_BLOCKS + 1, 1024, 0, stream>>>(
        batch, xpad, h1pad, tlen, w1, w2, w1t, w2t,
        g2, be2, lw, gwl, k12, durs, idxarr, tot, mel_out);
    gemm_k<0><<<dim3(256, 2), 256, 0, stream>>>(xpad, w1t, b1, yws,
                                                nullptr, nullptr, tlen);
    ln_kernel<<<8192, 256, 0, stream>>>(yws, g1, be1, h1pad, tlen);
    gemm_k<1><<<dim3(256, 2), 256, 0, stream>>>(h1pad, w2t, b2, nullptr,
                                                gwl, st2, tlen);
    gather_fin<<<32768 + 128, 256, 0, stream>>>(batch, idxarr, tot, out,
                                                st2, k12, lb, tlen, pred_out);
}